// Round 1
// 670.927 us; speedup vs baseline: 1.2009x; 1.2009x over previous
//
#include <hip/hip_runtime.h>
#include <stdint.h>

#define B_ROWS 1024
#define DDIM   2048
#define NFEAT  30000

// ---- 256x256 8-phase GEMM geometry (m201 template) ----
#define BM 256
#define BN 256
#define BK 64
#define GRID_M 4                    // 1024/256
#define GRID_N 118                  // ceil(30000/256)
#define NBLOCKS (GRID_M * GRID_N)   // 472 = 8*59 (exactly divisible by 8 XCDs)
#define NKT (DDIM / BK)             // 32 K-tiles

typedef __attribute__((ext_vector_type(8))) short short8;
typedef __attribute__((ext_vector_type(4))) float v4f;

typedef const __attribute__((address_space(1))) unsigned int* gptr_t;
typedef __attribute__((address_space(3))) unsigned int* lptr_t;

__device__ __forceinline__ unsigned short f32_to_bf16(float f) {
    unsigned int u = __float_as_uint(f);
    // round-to-nearest-even (inputs are finite gaussians; no NaN handling needed)
    unsigned int r = u + 0x7FFFu + ((u >> 16) & 1u);
    return (unsigned short)(r >> 16);
}

__device__ __forceinline__ void async_copy16(const void* g, void* l) {
    // global -> LDS direct copy, 16 B per lane; LDS dest = wave-uniform base + lane*16
    __builtin_amdgcn_global_load_lds((gptr_t)g, (lptr_t)l, 16, 0, 0);
}

// ---------------- convert f32 -> bf16 (vectorized, grid-stride) ----------------
__global__ void f32_to_bf16_kernel(const float4* __restrict__ src,
                                   ushort4* __restrict__ dst, int n4) {
    int stride = gridDim.x * blockDim.x;
    for (int i = blockIdx.x * blockDim.x + threadIdx.x; i < n4; i += stride) {
        float4 v = src[i];
        ushort4 o;
        o.x = f32_to_bf16(v.x);
        o.y = f32_to_bf16(v.y);
        o.z = f32_to_bf16(v.z);
        o.w = f32_to_bf16(v.w);
        dst[i] = o;
    }
}

// ---------------- fused: features f32 -> {bf16 scratch, f32 out1 copy} ----------------
// Reads features ONCE (saves a 245.8 MB re-read vs separate convert+copy kernels).
__global__ void fused_feat_kernel(const float4* __restrict__ src,
                                  ushort4* __restrict__ dstB,
                                  float4* __restrict__ dstF, int n4) {
    int stride = gridDim.x * blockDim.x;
    for (int i = blockIdx.x * blockDim.x + threadIdx.x; i < n4; i += stride) {
        float4 v = src[i];
        dstF[i] = v;
        ushort4 o;
        o.x = f32_to_bf16(v.x);
        o.y = f32_to_bf16(v.y);
        o.z = f32_to_bf16(v.z);
        o.w = f32_to_bf16(v.w);
        dstB[i] = o;
    }
}

// ---------------- f32 copy (fallback path only) ----------------
__global__ void copy_f32_kernel(const float4* __restrict__ src,
                                float4* __restrict__ dst, int n4) {
    int stride = gridDim.x * blockDim.x;
    for (int i = blockIdx.x * blockDim.x + threadIdx.x; i < n4; i += stride) {
        dst[i] = src[i];
    }
}

// ---------------- bf16 NT-GEMM, 256x256 tile, 8-phase counted-vmcnt schedule ----------------
// C[1024][30000] = A[1024][2048] * Bf[30000][2048]^T
// 8 waves (2m x 4n), per-wave output 128x64, 16x16x32 MFMA.
// LDS 128 KiB: A/B x dbuf-slot x half(128 rows), each half-tile [2 khalf][128 row][32 elem] bf16
// with st_16x32 swizzle (byte ^= ((byte>>9)&1)<<5) -> conflict-free-ish ds_read_b128.
// global_load_lds writes linearly; the swizzle is applied by pre-swizzling the GLOBAL
// source offset (involution), and on the ds_read addresses.
// Stage schedule per K-tile t: ph0:A1(t+1) ph1:B0(t+2) ph2:B1(t+2) ph3:A0(t+2) — each
// region's prefetch is issued only after the barrier following its last reader phase
// (A-half0 <-> frags 0-3 read ph0/ph1, A-half1 <-> frags 4-7 read ph2/ph3, B all read ph0),
// so slot reuse is structurally race-free. One s_waitcnt vmcnt(6) per K-tile boundary
// (3 half-tiles = 6 loads stay in flight across barriers).
__global__ __launch_bounds__(512, 2) void gemm_bf16_8ph(
    const unsigned short* __restrict__ A,   // [1024][2048] bf16
    const unsigned short* __restrict__ Bf,  // [30000][2048] bf16
    float* __restrict__ C)                  // [1024][30000] f32
{
    __shared__ alignas(16) unsigned char lds[131072];
    // A regions: lds + ((slot*2+half)<<14), 16 KB each (64 KB total)
    // B regions: lds + 65536 + ((slot*2+half)<<14)

    const int tid  = threadIdx.x;
    const int wave = tid >> 6;
    const int lane = tid & 63;
    const int wm   = wave >> 2;      // 0..1
    const int wn   = wave & 3;       // 0..3
    const int bh   = wn >> 1;        // which B half this wave reads (fixed)

    // XCD-chunked bijective swizzle: 472 = 8*59, m fastest within a chunk so the
    // 4 m-blocks of an n-stripe land on the same XCD L2.
    const int bid  = blockIdx.x;
    const int wgid = (bid & 7) * (NBLOCKS / 8) + (bid >> 3);
    const int mblk = wgid & (GRID_M - 1);
    const int nblk = wgid >> 2;

    const unsigned char* Ab = (const unsigned char*)A;
    const unsigned char* Bb = (const unsigned char*)Bf;

    // ---- staging source offsets: physical LDS chunk -> unswizzled logical (khalf,row,col)
    size_t a_src[2][2], b_src[2][2];   // [half][j]
    int ld_off[2];                     // wave-uniform LDS chunk offset
#pragma unroll
    for (int j = 0; j < 2; ++j) {
        const int P = (wave + j * 8) * 1024 + lane * 16;      // physical byte in half-tile
        const int Q = P ^ (((P >> 9) & 1) << 5);              // logical byte (involution)
        const int kh  = Q >> 13;                              // k-half (0..1)
        const int row = (Q >> 6) & 127;                       // row within half
        const int cb  = Q & 63;                               // byte within 32-elem row chunk
        ld_off[j] = (wave + j * 8) * 1024;
#pragma unroll
        for (int h = 0; h < 2; ++h) {
            const int ga = mblk * BM + h * 128 + row;          // < 1024 always
            int gb = nblk * BN + h * 128 + row;
            if (gb >= NFEAT) gb = NFEAT - 1;                   // clamp tail (stores guarded)
            a_src[h][j] = (size_t)ga * (DDIM * 2) + kh * 64 + cb;
            b_src[h][j] = (size_t)gb * (DDIM * 2) + kh * 64 + cb;
        }
    }

#define STAGE_A(kt, h) do {                                                         \
    unsigned char* _d = &lds[((((kt) & 1) * 2 + (h)) << 14)];                       \
    async_copy16(Ab + a_src[h][0] + (size_t)(kt) * 128, _d + ld_off[0]);            \
    async_copy16(Ab + a_src[h][1] + (size_t)(kt) * 128, _d + ld_off[1]);            \
} while (0)

#define STAGE_B(kt, h) do {                                                         \
    unsigned char* _d = &lds[65536 + ((((kt) & 1) * 2 + (h)) << 14)];               \
    async_copy16(Bb + b_src[h][0] + (size_t)(kt) * 128, _d + ld_off[0]);            \
    async_copy16(Bb + b_src[h][1] + (size_t)(kt) * 128, _d + ld_off[1]);            \
} while (0)

    // ---- fragment ds_read offsets (within a 16 KB half-tile region, ks=0; ks=1 adds 8192)
    // A frag f: half = f>>2, row-in-half = (f&3)*32 + wm*16 + (lane&15)
    // B frag n: half = bh,   row-in-half = (wn&1)*64 + n*16 + (lane&15)
    int aoff[4], boff[4];
#pragma unroll
    for (int j = 0; j < 4; ++j) {
        const int ar = j * 32 + wm * 16 + (lane & 15);
        const int aq = ar * 64 + (lane >> 4) * 16;
        aoff[j] = aq ^ (((ar >> 3) & 1) << 5);
        const int br = (wn & 1) * 64 + j * 16 + (lane & 15);
        const int bq = br * 64 + (lane >> 4) * 16;
        boff[j] = bq ^ (((br >> 3) & 1) << 5);
    }

#define READ_A(slot, f, ks) \
    (*(const short8*)&lds[((((slot) * 2) + ((f) >> 2)) << 14) + (ks) * 8192 + aoff[(f) & 3]])
#define READ_B(slot, n, ks) \
    (*(const short8*)&lds[65536 + ((((slot) * 2) + bh) << 14) + (ks) * 8192 + boff[n]])

    v4f acc[8][4];
#pragma unroll
    for (int f = 0; f < 8; ++f)
#pragma unroll
        for (int n = 0; n < 4; ++n)
            acc[f][n] = (v4f){0.f, 0.f, 0.f, 0.f};

    short8 af[2][2];   // 2 m-frags x 2 k-steps (per phase)
    short8 bfr[4][2];  // 4 n-frags x 2 k-steps (per K-tile, read in phase 0)

#define MFMA_QUAD(f0) do {                                                                             \
    _Pragma("unroll")                                                                                  \
    for (int n = 0; n < 4; ++n) {                                                                      \
        acc[(f0)][n]     = __builtin_amdgcn_mfma_f32_16x16x32_bf16(af[0][0], bfr[n][0], acc[(f0)][n],     0, 0, 0); \
        acc[(f0)][n]     = __builtin_amdgcn_mfma_f32_16x16x32_bf16(af[0][1], bfr[n][1], acc[(f0)][n],     0, 0, 0); \
        acc[(f0) + 1][n] = __builtin_amdgcn_mfma_f32_16x16x32_bf16(af[1][0], bfr[n][0], acc[(f0) + 1][n], 0, 0, 0); \
        acc[(f0) + 1][n] = __builtin_amdgcn_mfma_f32_16x16x32_bf16(af[1][1], bfr[n][1], acc[(f0) + 1][n], 0, 0, 0); \
    }                                                                                                  \
} while (0)

    // ---- prologue: stage 7 half-tiles (steady-state history), keep last 3 in flight
    STAGE_B(0, 0); STAGE_B(0, 1); STAGE_A(0, 0); STAGE_A(0, 1);
    STAGE_B(1, 0); STAGE_B(1, 1); STAGE_A(1, 0);
    asm volatile("s_waitcnt vmcnt(6)" ::: "memory");
    __builtin_amdgcn_s_barrier();

    for (int t = 0; t < NKT; ++t) {
        const int slot = t & 1;

        // ---------- phase 0: A frags 0,1 + all 8 B frags; stage A1(t+1) ----------
        af[0][0] = READ_A(slot, 0, 0); af[0][1] = READ_A(slot, 0, 1);
        af[1][0] = READ_A(slot, 1, 0); af[1][1] = READ_A(slot, 1, 1);
#pragma unroll
        for (int n = 0; n < 4; ++n) {
            bfr[n][0] = READ_B(slot, n, 0);
            bfr[n][1] = READ_B(slot, n, 1);
        }
        if (t + 1 < NKT) STAGE_A(t + 1, 1);
        asm volatile("s_waitcnt lgkmcnt(8)" ::: "memory");
        __builtin_amdgcn_s_barrier();
        asm volatile("s_waitcnt lgkmcnt(0)" ::: "memory");
        __builtin_amdgcn_s_setprio(1);
        MFMA_QUAD(0);
        __builtin_amdgcn_s_setprio(0);
        __builtin_amdgcn_s_barrier();

        // ---------- phase 1: A frags 2,3; stage B0(t+2) ----------
        af[0][0] = READ_A(slot, 2, 0); af[0][1] = READ_A(slot, 2, 1);
        af[1][0] = READ_A(slot, 3, 0); af[1][1] = READ_A(slot, 3, 1);
        if (t + 2 < NKT) STAGE_B(t + 2, 0);
        __builtin_amdgcn_s_barrier();
        asm volatile("s_waitcnt lgkmcnt(0)" ::: "memory");
        __builtin_amdgcn_s_setprio(1);
        MFMA_QUAD(2);
        __builtin_amdgcn_s_setprio(0);
        __builtin_amdgcn_s_barrier();

        // ---------- phase 2: A frags 4,5; stage B1(t+2) ----------
        af[0][0] = READ_A(slot, 4, 0); af[0][1] = READ_A(slot, 4, 1);
        af[1][0] = READ_A(slot, 5, 0); af[1][1] = READ_A(slot, 5, 1);
        if (t + 2 < NKT) STAGE_B(t + 2, 1);
        __builtin_amdgcn_s_barrier();
        asm volatile("s_waitcnt lgkmcnt(0)" ::: "memory");
        __builtin_amdgcn_s_setprio(1);
        MFMA_QUAD(4);
        __builtin_amdgcn_s_setprio(0);
        __builtin_amdgcn_s_barrier();

        // ---------- phase 3: A frags 6,7; stage A0(t+2); K-tile boundary vmcnt ----------
        af[0][0] = READ_A(slot, 6, 0); af[0][1] = READ_A(slot, 6, 1);
        af[1][0] = READ_A(slot, 7, 0); af[1][1] = READ_A(slot, 7, 1);
        if (t + 2 < NKT) STAGE_A(t + 2, 0);
        __builtin_amdgcn_s_barrier();
        asm volatile("s_waitcnt lgkmcnt(0)" ::: "memory");
        __builtin_amdgcn_s_setprio(1);
        MFMA_QUAD(6);
        __builtin_amdgcn_s_setprio(0);
        if (t < NKT - 2) {
            asm volatile("s_waitcnt vmcnt(6)" ::: "memory");   // keep 3 half-tiles in flight
        } else if (t == NKT - 2) {
            asm volatile("s_waitcnt vmcnt(0)" ::: "memory");   // drain for the last K-tile
        }
        __builtin_amdgcn_s_barrier();
    }

    // ---- epilogue: C/D layout col = lane&15, row = (lane>>4)*4 + r
    // frag f covers global rows mblk*256 + f*32 + wm*16 + 0..15
#pragma unroll
    for (int f = 0; f < 8; ++f) {
        const int gr = mblk * BM + f * 32 + wm * 16 + (lane >> 4) * 4;
#pragma unroll
        for (int n = 0; n < 4; ++n) {
            const int gc = nblk * BN + wn * 64 + n * 16 + (lane & 15);
            if (gc < NFEAT) {
#pragma unroll
                for (int r = 0; r < 4; ++r)
                    C[(size_t)(gr + r) * NFEAT + gc] = acc[f][n][r];
            }
        }
    }
#undef STAGE_A
#undef STAGE_B
#undef READ_A
#undef READ_B
#undef MFMA_QUAD
}

// ---------------- scatter: last-writer-wins row overwrite ----------------
__global__ void scatter_rows_kernel(const float* __restrict__ inputs,
                                    const int* __restrict__ idx,
                                    const int* __restrict__ uf,
                                    float* __restrict__ out_feats) {
    int b = blockIdx.x;
    if (uf[b] <= 0) return;
    int y = idx[b];
    __shared__ int dead;
    if (threadIdx.x == 0) dead = 0;
    __syncthreads();
    for (int b2 = b + 1 + threadIdx.x; b2 < B_ROWS; b2 += blockDim.x) {
        if (uf[b2] > 0 && idx[b2] == y) { dead = 1; break; }
    }
    __syncthreads();
    if (dead) return;
    // winner: overwrite row y with inputs[b] (already unit-norm; renorm is a ~1e-7 no-op)
    const float4* s = (const float4*)(inputs + (size_t)b * DDIM);
    float4* d = (float4*)(out_feats + (size_t)y * DDIM);
    for (int i = threadIdx.x; i < DDIM / 4; i += blockDim.x) d[i] = s[i];
}

extern "C" void kernel_launch(void* const* d_in, const int* in_sizes, int n_in,
                              void* d_out, int out_size, void* d_ws, size_t ws_size,
                              hipStream_t stream) {
    const float* inputs   = (const float*)d_in[0];   // [1024][2048]
    const float* features = (const float*)d_in[1];   // [30000][2048]
    // d_in[2] = IoU (unused by max_iou path)
    const int* indexes    = (const int*)d_in[3];     // [1024] (int32: jax x64 disabled)
    const int* uf         = (const int*)d_in[4];     // [1024]

    float* out0 = (float*)d_out;                         // [1024][30000]
    float* out1 = out0 + (size_t)B_ROWS * NFEAT;         // [30000][2048]

    const int nf4 = NFEAT * DDIM / 4;    // 15,360,000
    const int na4 = B_ROWS * DDIM / 4;   // 524,288

    const size_t featB_bytes = (size_t)NFEAT * DDIM * 2;   // 122.88 MB
    const size_t inpB_bytes  = (size_t)B_ROWS * DDIM * 2;  // 4.19 MB

    if (d_ws && ws_size >= featB_bytes + inpB_bytes) {
        // Preferred: bf16 scratch in workspace -> convert and f32-copy fuse into one
        // pass over features (reads features once instead of twice).
        unsigned short* featB = (unsigned short*)d_ws;
        unsigned short* inpB  = (unsigned short*)((char*)d_ws + featB_bytes);

        fused_feat_kernel<<<4096, 256, 0, stream>>>((const float4*)features,
                                                    (ushort4*)featB, (float4*)out1, nf4);
        f32_to_bf16_kernel<<<2048, 256, 0, stream>>>((const float4*)inputs, (ushort4*)inpB, na4);
        gemm_bf16_8ph<<<NBLOCKS, 512, 0, stream>>>(inpB, featB, out0);
        scatter_rows_kernel<<<B_ROWS, 256, 0, stream>>>(inputs, indexes, uf, out1);
    } else {
        // Fallback (small workspace): bf16 scratch inside out1, overwritten by the
        // f32 copy AFTER the GEMM (stream-ordered), as in the previous version.
        unsigned short* featB = (unsigned short*)out1;
        unsigned short* inpB  = featB + (size_t)NFEAT * DDIM;

        f32_to_bf16_kernel<<<8192, 256, 0, stream>>>((const float4*)features, (ushort4*)featB, nf4);
        f32_to_bf16_kernel<<<2048, 256, 0, stream>>>((const float4*)inputs, (ushort4*)inpB, na4);
        gemm_bf16_8ph<<<NBLOCKS, 512, 0, stream>>>(inpB, featB, out0);
        copy_f32_kernel<<<8192, 256, 0, stream>>>((const float4*)features, (float4*)out1, nf4);
        scatter_rows_kernel<<<B_ROWS, 256, 0, stream>>>(inputs, indexes, uf, out1);
    }
}

// Round 3
// 648.352 us; speedup vs baseline: 1.2427x; 1.0348x over previous
//
#include <hip/hip_runtime.h>
#include <stdint.h>

#define B_ROWS 1024
#define DDIM   2048
#define NFEAT  30000

// ---- 256x256 8-phase GEMM geometry (m201 template) ----
#define BM 256
#define BN 256
#define BK 64
#define GRID_M 4                    // 1024/256
#define GRID_N 118                  // ceil(30000/256)
#define NBLOCKS (GRID_M * GRID_N)   // 472 = 8*59 (exactly divisible by 8 XCDs)
#define NKT (DDIM / BK)             // 32 K-tiles

typedef __attribute__((ext_vector_type(8))) short short8;
typedef __attribute__((ext_vector_type(4))) float v4f;
typedef __attribute__((ext_vector_type(4))) unsigned short u16x4;

typedef const __attribute__((address_space(1))) unsigned int* gptr_t;
typedef __attribute__((address_space(3))) unsigned int* lptr_t;

__device__ __forceinline__ unsigned short f32_to_bf16(float f) {
    unsigned int u = __float_as_uint(f);
    // round-to-nearest-even (inputs are finite gaussians; no NaN handling needed)
    unsigned int r = u + 0x7FFFu + ((u >> 16) & 1u);
    return (unsigned short)(r >> 16);
}

__device__ __forceinline__ void async_copy16(const void* g, void* l) {
    // global -> LDS direct copy, 16 B per lane; LDS dest = wave-uniform base + lane*16
    __builtin_amdgcn_global_load_lds((gptr_t)g, (lptr_t)l, 16, 0, 0);
}

// ---------------- convert f32 -> bf16 (vectorized, grid-stride) ----------------
__global__ void f32_to_bf16_kernel(const float4* __restrict__ src,
                                   ushort4* __restrict__ dst, int n4) {
    int stride = gridDim.x * blockDim.x;
    for (int i = blockIdx.x * blockDim.x + threadIdx.x; i < n4; i += stride) {
        float4 v = src[i];
        ushort4 o;
        o.x = f32_to_bf16(v.x);
        o.y = f32_to_bf16(v.y);
        o.z = f32_to_bf16(v.z);
        o.w = f32_to_bf16(v.w);
        dst[i] = o;
    }
}

// ---------------- fused: features f32 -> {bf16 scratch, f32 out1 copy} ----------------
// Reads features ONCE. Nontemporal on the f32 stream (never re-read) so featB
// (consumed next by the GEMM) stays L2/LLC-resident. Uses native ext-vector v4f
// for the nontemporal builtins (HIP_vector_type float4 is a class -> rejected).
__global__ void fused_feat_kernel(const v4f* __restrict__ src,
                                  u16x4* __restrict__ dstB,
                                  v4f* __restrict__ dstF, int n4) {
    int stride = gridDim.x * blockDim.x;
    for (int i = blockIdx.x * blockDim.x + threadIdx.x; i < n4; i += stride) {
        v4f v = __builtin_nontemporal_load(&src[i]);
        __builtin_nontemporal_store(v, &dstF[i]);
        u16x4 o;
        o.x = f32_to_bf16(v.x);
        o.y = f32_to_bf16(v.y);
        o.z = f32_to_bf16(v.z);
        o.w = f32_to_bf16(v.w);
        dstB[i] = o;   // regular store: GEMM reads this next
    }
}

// ---------------- f32 copy (fallback path only) ----------------
__global__ void copy_f32_kernel(const float4* __restrict__ src,
                                float4* __restrict__ dst, int n4) {
    int stride = gridDim.x * blockDim.x;
    for (int i = blockIdx.x * blockDim.x + threadIdx.x; i < n4; i += stride) {
        dst[i] = src[i];
    }
}

// ---------------- bf16 NT-GEMM, 256x256 tile, 8-phase counted-vmcnt schedule ----------------
// C[1024][30000] = A[1024][2048] * Bf[30000][2048]^T
// 8 waves (2m x 4n), per-wave output 128x64, 16x16x32 MFMA.
// LDS 128 KiB: A/B x dbuf-slot x half(128 rows); each 16 KiB region = [128 row][128 B]
// (full BK=64 contiguous per row — contiguous in global too, so global_load_lds applies).
// Bank-conflict swizzle (G4/m214 geometry): byte ^= ((row&7)<<4). gload_lds writes
// linearly, so the swizzle is realized by pre-swizzling the GLOBAL source byte within
// each 128 B row (involution) and applying the same XOR on ds_read addresses.
// This spreads a 16-lane read group over all 8 16-B slots (2 lanes/slot = conflict-free
// per m136) vs the previous layout's 4-way.
// Stage schedule per K-tile t: ph0:A1(t+1) ph1:B0(t+2) ph2:B1(t+2) ph3:A0(t+2) — each
// region's prefetch is issued only after the barrier following its last reader phase,
// so slot reuse is structurally race-free. One s_waitcnt vmcnt(6) per K-tile boundary
// (3 half-tiles = 6 loads stay in flight across barriers).
__global__ __launch_bounds__(512, 2) void gemm_bf16_8ph(
    const unsigned short* __restrict__ A,   // [1024][2048] bf16
    const unsigned short* __restrict__ Bf,  // [30000][2048] bf16
    float* __restrict__ C)                  // [1024][30000] f32
{
    __shared__ alignas(16) unsigned char lds[131072];
    // A regions: lds + ((slot*2+half)<<14), 16 KB each (64 KB total)
    // B regions: lds + 65536 + ((slot*2+half)<<14)

    const int tid  = threadIdx.x;
    const int wave = tid >> 6;
    const int lane = tid & 63;
    const int wm   = wave >> 2;      // 0..1
    const int wn   = wave & 3;       // 0..3
    const int bh   = wn >> 1;        // which B half this wave reads (fixed)

    // XCD-chunked bijective swizzle: 472 = 8*59, m fastest within a chunk so the
    // 4 m-blocks of an n-stripe land on the same XCD L2.
    const int bid  = blockIdx.x;
    const int wgid = (bid & 7) * (NBLOCKS / 8) + (bid >> 3);
    const int mblk = wgid & (GRID_M - 1);
    const int nblk = wgid >> 2;

    const unsigned char* Ab = (const unsigned char*)A;
    const unsigned char* Bb = (const unsigned char*)Bf;

    // ---- staging source offsets ----
    // Physical LDS byte for chunk c, lane l: P = c*1024 + l*16 -> region row = c*8 + (l>>3),
    // physical slot = l&7. Logical slot stored there = (l&7) ^ (row&7) = (l&7) ^ (l>>3).
    size_t a_src[2][2], b_src[2][2];   // [half][j]
    int ld_off[2];                     // wave-uniform LDS chunk offset
#pragma unroll
    for (int j = 0; j < 2; ++j) {
        const int chunk = wave + j * 8;
        ld_off[j] = chunk * 1024;
        const int rrow = chunk * 8 + (lane >> 3);               // region row 0..127
        const int cb   = (((lane & 7) ^ (lane >> 3)) * 16);     // pre-swizzled byte in row
#pragma unroll
        for (int h = 0; h < 2; ++h) {
            const int ga = mblk * BM + h * 128 + rrow;           // < 1024 always
            int gb = nblk * BN + h * 128 + rrow;
            if (gb >= NFEAT) gb = NFEAT - 1;                     // clamp tail (stores guarded)
            a_src[h][j] = (size_t)ga * (DDIM * 2) + cb;
            b_src[h][j] = (size_t)gb * (DDIM * 2) + cb;
        }
    }

#define STAGE_A(kt, h) do {                                                         \
    unsigned char* _d = &lds[((((kt) & 1) * 2 + (h)) << 14)];                       \
    async_copy16(Ab + a_src[h][0] + (size_t)(kt) * 128, _d + ld_off[0]);            \
    async_copy16(Ab + a_src[h][1] + (size_t)(kt) * 128, _d + ld_off[1]);            \
} while (0)

#define STAGE_B(kt, h) do {                                                         \
    unsigned char* _d = &lds[65536 + ((((kt) & 1) * 2 + (h)) << 14)];               \
    async_copy16(Bb + b_src[h][0] + (size_t)(kt) * 128, _d + ld_off[0]);            \
    async_copy16(Bb + b_src[h][1] + (size_t)(kt) * 128, _d + ld_off[1]);            \
} while (0)

    // ---- fragment ds_read offsets (within a 16 KB region)
    // A frag f: region half = f>>2, row = (f&3)*32 + wm*16 + (lane&15)
    // B frag n: region half = bh,   row = (wn&1)*64 + n*16 + (lane&15)
    // Logical byte-in-row = ks*64 + (lane>>4)*16; physical = row*128 + (slot^(row&7))*16.
    int aoff[4][2], boff[4][2];
#pragma unroll
    for (int j = 0; j < 4; ++j) {
#pragma unroll
        for (int ks = 0; ks < 2; ++ks) {
            const int ar = j * 32 + wm * 16 + (lane & 15);
            const int as = ((lane >> 4) + 4 * ks) ^ (ar & 7);
            aoff[j][ks] = ar * 128 + as * 16;
            const int br = (wn & 1) * 64 + j * 16 + (lane & 15);
            const int bs = ((lane >> 4) + 4 * ks) ^ (br & 7);
            boff[j][ks] = br * 128 + bs * 16;
        }
    }

#define READ_A(slot, f, ks) \
    (*(const short8*)&lds[((((slot) * 2) + ((f) >> 2)) << 14) + aoff[(f) & 3][ks]])
#define READ_B(slot, n, ks) \
    (*(const short8*)&lds[65536 + ((((slot) * 2) + bh) << 14) + boff[n][ks]])

    v4f acc[8][4];
#pragma unroll
    for (int f = 0; f < 8; ++f)
#pragma unroll
        for (int n = 0; n < 4; ++n)
            acc[f][n] = (v4f){0.f, 0.f, 0.f, 0.f};

    short8 af[2][2];   // 2 m-frags x 2 k-steps (per phase)
    short8 bfr[4][2];  // 4 n-frags x 2 k-steps (per K-tile, read in phase 0)

#define MFMA_QUAD(f0) do {                                                                             \
    _Pragma("unroll")                                                                                  \
    for (int n = 0; n < 4; ++n) {                                                                      \
        acc[(f0)][n]     = __builtin_amdgcn_mfma_f32_16x16x32_bf16(af[0][0], bfr[n][0], acc[(f0)][n],     0, 0, 0); \
        acc[(f0)][n]     = __builtin_amdgcn_mfma_f32_16x16x32_bf16(af[0][1], bfr[n][1], acc[(f0)][n],     0, 0, 0); \
        acc[(f0) + 1][n] = __builtin_amdgcn_mfma_f32_16x16x32_bf16(af[1][0], bfr[n][0], acc[(f0) + 1][n], 0, 0, 0); \
        acc[(f0) + 1][n] = __builtin_amdgcn_mfma_f32_16x16x32_bf16(af[1][1], bfr[n][1], acc[(f0) + 1][n], 0, 0, 0); \
    }                                                                                                  \
} while (0)

    // ---- prologue: stage 7 half-tiles (steady-state history), keep last 3 in flight
    STAGE_B(0, 0); STAGE_B(0, 1); STAGE_A(0, 0); STAGE_A(0, 1);
    STAGE_B(1, 0); STAGE_B(1, 1); STAGE_A(1, 0);
    asm volatile("s_waitcnt vmcnt(6)" ::: "memory");
    __builtin_amdgcn_s_barrier();

    for (int t = 0; t < NKT; ++t) {
        const int slot = t & 1;

        // ---------- phase 0: A frags 0,1 + all 8 B frags; stage A1(t+1) ----------
        af[0][0] = READ_A(slot, 0, 0); af[0][1] = READ_A(slot, 0, 1);
        af[1][0] = READ_A(slot, 1, 0); af[1][1] = READ_A(slot, 1, 1);
#pragma unroll
        for (int n = 0; n < 4; ++n) {
            bfr[n][0] = READ_B(slot, n, 0);
            bfr[n][1] = READ_B(slot, n, 1);
        }
        if (t + 1 < NKT) STAGE_A(t + 1, 1);
        asm volatile("s_waitcnt lgkmcnt(8)" ::: "memory");
        __builtin_amdgcn_s_barrier();
        asm volatile("s_waitcnt lgkmcnt(0)" ::: "memory");
        __builtin_amdgcn_s_setprio(1);
        MFMA_QUAD(0);
        __builtin_amdgcn_s_setprio(0);
        __builtin_amdgcn_s_barrier();

        // ---------- phase 1: A frags 2,3; stage B0(t+2) ----------
        af[0][0] = READ_A(slot, 2, 0); af[0][1] = READ_A(slot, 2, 1);
        af[1][0] = READ_A(slot, 3, 0); af[1][1] = READ_A(slot, 3, 1);
        if (t + 2 < NKT) STAGE_B(t + 2, 0);
        __builtin_amdgcn_s_barrier();
        asm volatile("s_waitcnt lgkmcnt(0)" ::: "memory");
        __builtin_amdgcn_s_setprio(1);
        MFMA_QUAD(2);
        __builtin_amdgcn_s_setprio(0);
        __builtin_amdgcn_s_barrier();

        // ---------- phase 2: A frags 4,5; stage B1(t+2) ----------
        af[0][0] = READ_A(slot, 4, 0); af[0][1] = READ_A(slot, 4, 1);
        af[1][0] = READ_A(slot, 5, 0); af[1][1] = READ_A(slot, 5, 1);
        if (t + 2 < NKT) STAGE_B(t + 2, 1);
        __builtin_amdgcn_s_barrier();
        asm volatile("s_waitcnt lgkmcnt(0)" ::: "memory");
        __builtin_amdgcn_s_setprio(1);
        MFMA_QUAD(4);
        __builtin_amdgcn_s_setprio(0);
        __builtin_amdgcn_s_barrier();

        // ---------- phase 3: A frags 6,7; stage A0(t+2); K-tile boundary vmcnt ----------
        af[0][0] = READ_A(slot, 6, 0); af[0][1] = READ_A(slot, 6, 1);
        af[1][0] = READ_A(slot, 7, 0); af[1][1] = READ_A(slot, 7, 1);
        if (t + 2 < NKT) STAGE_A(t + 2, 0);
        __builtin_amdgcn_s_barrier();
        asm volatile("s_waitcnt lgkmcnt(0)" ::: "memory");
        __builtin_amdgcn_s_setprio(1);
        MFMA_QUAD(6);
        __builtin_amdgcn_s_setprio(0);
        if (t < NKT - 2) {
            asm volatile("s_waitcnt vmcnt(6)" ::: "memory");   // keep 3 half-tiles in flight
        } else if (t == NKT - 2) {
            asm volatile("s_waitcnt vmcnt(0)" ::: "memory");   // drain for the last K-tile
        }
        __builtin_amdgcn_s_barrier();
    }

    // ---- epilogue: C/D layout col = lane&15, row = (lane>>4)*4 + r
    // frag f covers global rows mblk*256 + f*32 + wm*16 + 0..15
#pragma unroll
    for (int f = 0; f < 8; ++f) {
        const int gr = mblk * BM + f * 32 + wm * 16 + (lane >> 4) * 4;
#pragma unroll
        for (int n = 0; n < 4; ++n) {
            const int gc = nblk * BN + wn * 64 + n * 16 + (lane & 15);
            if (gc < NFEAT) {
#pragma unroll
                for (int r = 0; r < 4; ++r)
                    C[(size_t)(gr + r) * NFEAT + gc] = acc[f][n][r];
            }
        }
    }
#undef STAGE_A
#undef STAGE_B
#undef READ_A
#undef READ_B
#undef MFMA_QUAD
}

// ---------------- scatter: last-writer-wins row overwrite ----------------
__global__ void scatter_rows_kernel(const float* __restrict__ inputs,
                                    const int* __restrict__ idx,
                                    const int* __restrict__ uf,
                                    float* __restrict__ out_feats) {
    int b = blockIdx.x;
    if (uf[b] <= 0) return;
    int y = idx[b];
    __shared__ int dead;
    if (threadIdx.x == 0) dead = 0;
    __syncthreads();
    for (int b2 = b + 1 + threadIdx.x; b2 < B_ROWS; b2 += blockDim.x) {
        if (uf[b2] > 0 && idx[b2] == y) { dead = 1; break; }
    }
    __syncthreads();
    if (dead) return;
    // winner: overwrite row y with inputs[b] (already unit-norm; renorm is a ~1e-7 no-op)
    const float4* s = (const float4*)(inputs + (size_t)b * DDIM);
    float4* d = (float4*)(out_feats + (size_t)y * DDIM);
    for (int i = threadIdx.x; i < DDIM / 4; i += blockDim.x) d[i] = s[i];
}

extern "C" void kernel_launch(void* const* d_in, const int* in_sizes, int n_in,
                              void* d_out, int out_size, void* d_ws, size_t ws_size,
                              hipStream_t stream) {
    const float* inputs   = (const float*)d_in[0];   // [1024][2048]
    const float* features = (const float*)d_in[1];   // [30000][2048]
    // d_in[2] = IoU (unused by max_iou path)
    const int* indexes    = (const int*)d_in[3];     // [1024]
    const int* uf         = (const int*)d_in[4];     // [1024]

    float* out0 = (float*)d_out;                         // [1024][30000]
    float* out1 = out0 + (size_t)B_ROWS * NFEAT;         // [30000][2048]

    const int nf4 = NFEAT * DDIM / 4;    // 15,360,000
    const int na4 = B_ROWS * DDIM / 4;   // 524,288

    const size_t featB_bytes = (size_t)NFEAT * DDIM * 2;   // 122.88 MB
    const size_t inpB_bytes  = (size_t)B_ROWS * DDIM * 2;  // 4.19 MB

    if (d_ws && ws_size >= featB_bytes + inpB_bytes) {
        // Preferred: bf16 scratch in workspace -> convert and f32-copy fuse into one
        // pass over features (reads features once instead of twice).
        unsigned short* featB = (unsigned short*)d_ws;
        unsigned short* inpB  = (unsigned short*)((char*)d_ws + featB_bytes);

        fused_feat_kernel<<<4096, 256, 0, stream>>>((const v4f*)features,
                                                    (u16x4*)featB, (v4f*)out1, nf4);
        f32_to_bf16_kernel<<<2048, 256, 0, stream>>>((const float4*)inputs, (ushort4*)inpB, na4);
        gemm_bf16_8ph<<<NBLOCKS, 512, 0, stream>>>(inpB, featB, out0);
        scatter_rows_kernel<<<B_ROWS, 256, 0, stream>>>(inputs, indexes, uf, out1);
    } else {
        // Fallback (small workspace): bf16 scratch inside out1, overwritten by the
        // f32 copy AFTER the GEMM (stream-ordered).
        unsigned short* featB = (unsigned short*)out1;
        unsigned short* inpB  = featB + (size_t)NFEAT * DDIM;

        f32_to_bf16_kernel<<<8192, 256, 0, stream>>>((const float4*)features, (ushort4*)featB, nf4);
        f32_to_bf16_kernel<<<2048, 256, 0, stream>>>((const float4*)inputs, (ushort4*)inpB, na4);
        gemm_bf16_8ph<<<NBLOCKS, 512, 0, stream>>>(inpB, featB, out0);
        copy_f32_kernel<<<8192, 256, 0, stream>>>((const float4*)features, (float4*)out1, nf4);
        scatter_rows_kernel<<<B_ROWS, 256, 0, stream>>>(inputs, indexes, uf, out1);
    }
}